// Round 6
// baseline (556.888 us; speedup 1.0000x reference)
//
#include <hip/hip_runtime.h>
#include <math.h>

constexpr int N_NODES = 100000;
constexpr int N_EDGES = 1600000;
constexpr int E_TOT   = N_EDGES + N_NODES;
constexpr int F_IN    = 128;
constexpr int F_H     = 64;
constexpr float NEG_SLOPE = 0.2f;

constexpr int NBUCK  = (N_NODES + 255) / 256;  // 391 buckets of 256 dst nodes
constexpr int SUB    = 8;                      // sub-streams per bucket
constexpr int SUBCAP = 1024;                   // mean 512 (real edges only), +22 sigma
constexpr int LCAP   = 6144;                   // bucket mean 4096, +32 sigma

__device__ inline float lrelu(float v) { return v > 0.f ? v : NEG_SLOPE * v; }

// ---------------- GEMM: lane = row, W via wave-uniform scalar loads, no LDS ----------------
__global__ __launch_bounds__(64) void k_gemm1(
    const float* __restrict__ x, const float* __restrict__ W1,
    const float* __restrict__ a_s, const float* __restrict__ a_d,
    float* __restrict__ h1, float* __restrict__ as1, float* __restrict__ ad1)
{
    const int row = blockIdx.x * 64 + threadIdx.x;
    if (row >= N_NODES) return;

    float acc[F_H];
#pragma unroll
    for (int f = 0; f < F_H; ++f) acc[f] = 0.f;

    const float4* __restrict__ xr = (const float4*)(x + (size_t)row * F_IN);
    for (int k4 = 0; k4 < F_IN / 4; ++k4) {
        const float4 xv = xr[k4];
        const float* __restrict__ wk = W1 + (size_t)k4 * 4 * F_H;
#pragma unroll
        for (int kk = 0; kk < 4; ++kk) {
            const float xs = (kk == 0) ? xv.x : (kk == 1) ? xv.y : (kk == 2) ? xv.z : xv.w;
            const float* __restrict__ w = wk + kk * F_H;   // wave-uniform -> scalar loads
#pragma unroll
            for (int f = 0; f < F_H; ++f)
                acc[f] = fmaf(xs, w[f], acc[f]);
        }
    }

    float vs = 0.f, vd = 0.f;
#pragma unroll
    for (int f = 0; f < F_H; ++f) {
        vs = fmaf(acc[f], a_s[f], vs);
        vd = fmaf(acc[f], a_d[f], vd);
    }
    as1[row] = vs;
    ad1[row] = vd;

    float4* __restrict__ hr = (float4*)(h1 + (size_t)row * F_H);
#pragma unroll
    for (int q = 0; q < F_H / 4; ++q)
        hr[q] = make_float4(acc[4 * q], acc[4 * q + 1], acc[4 * q + 2], acc[4 * q + 3]);
}

// ---------------- Pass S1: bucketize REAL edges only (self-loops implicit) ----------------
__global__ __launch_bounds__(256) void k_bucketize(
    const int* __restrict__ ei, int* __restrict__ bcur, unsigned* __restrict__ buf)
{
    const int i = blockIdx.x * 256 + threadIdx.x;
    if (i >= N_EDGES) return;
    const int s = ei[i], d = ei[N_EDGES + i];
    const int b = d >> 8;
    const int c = b * SUB + (blockIdx.x & (SUB - 1));
    const int pos = atomicAdd(&bcur[c], 1);
    if (pos < SUBCAP)
        buf[(size_t)c * SUBCAP + pos] = ((unsigned)s << 8) | (unsigned)(d & 255);
}

// ---------------- Bucket-total scan (391 values, one block) ----------------
__global__ __launch_bounds__(512) void k_bscan(const int* __restrict__ bcur, int* __restrict__ boff)
{
    __shared__ int sm[512];
    const int t = threadIdx.x;
    int m = 0;
    if (t < NBUCK) {
#pragma unroll
        for (int q = 0; q < SUB; ++q) m += min(bcur[t * SUB + q], SUBCAP);
    }
    sm[t] = m;
    __syncthreads();
    for (int o = 1; o < 512; o <<= 1) {
        int a = (t >= o) ? sm[t - o] : 0;
        __syncthreads();
        sm[t] += a;
        __syncthreads();
    }
    if (t < NBUCK) boff[t] = sm[t] - m;   // exclusive
}

// ---------------- Pass S2: per-bucket CSR in LDS + fused layer-1 aggregate ----------------
// CSR holds REAL edges; the self edge (src=n) is added explicitly in the softmax.
__global__ __launch_bounds__(256) void k_csr_agg1(
    const int* __restrict__ bcur, const unsigned* __restrict__ buf, const int* __restrict__ boff,
    const float* __restrict__ as1, const float* __restrict__ ad1, const float* __restrict__ h1,
    const float* __restrict__ b1, const float* __restrict__ W2,
    const float* __restrict__ a_s2, const float* __restrict__ a_d2,
    int* __restrict__ row_start, int* __restrict__ csr,
    float* __restrict__ h2, float* __restrict__ as2, float* __restrict__ ad2)
{
    __shared__ int lcsr[LCAP];      // 24 KB
    __shared__ int hist[256];
    __shared__ int lstart[257];
    __shared__ int lcur[256];
    __shared__ int scnt[SUB];

    const int b  = blockIdx.x;
    const int t  = threadIdx.x;
    const int nd = min(256, N_NODES - (b << 8));

    hist[t] = 0;
    if (t < SUB) scnt[t] = min(bcur[b * SUB + t], SUBCAP);
    __syncthreads();

    // 1. histogram of local dst
    for (int q = 0; q < SUB; ++q) {
        const unsigned* __restrict__ sb = buf + (size_t)(b * SUB + q) * SUBCAP;
        const int m = scnt[q];
        for (int i = t; i < m; i += 256) atomicAdd(&hist[sb[i] & 255], 1);
    }
    __syncthreads();

    // 2. inclusive scan -> lstart
    for (int o = 1; o < 256; o <<= 1) {
        int a = (t >= o) ? hist[t - o] : 0;
        __syncthreads();
        hist[t] += a;
        __syncthreads();
    }
    if (t == 0) lstart[0] = 0;
    lstart[t + 1] = hist[t];
    lcur[t] = 0;
    __syncthreads();

    // 3. scatter src ids into LDS csr
    for (int q = 0; q < SUB; ++q) {
        const unsigned* __restrict__ sb = buf + (size_t)(b * SUB + q) * SUBCAP;
        const int m = scnt[q];
        for (int i = t; i < m; i += 256) {
            const unsigned v = sb[i];
            const int dl = v & 255;
            const int p  = atomicAdd(&lcur[dl], 1);
            const int pp = lstart[dl] + p;
            if (pp < LCAP) lcsr[pp] = (int)(v >> 8);
        }
    }
    __syncthreads();

    // 4. write global csr (dense) + row_start (real edges only)
    const int gb   = boff[b];
    const int mtot = lstart[256];
    for (int i = t; i < mtot; i += 256) csr[gb + i] = lcsr[i];
    if (t < nd) row_start[(b << 8) + t + 1] = gb + lstart[t + 1];
    if (b == 0 && t == 0) row_start[0] = 0;

    // 5. fused layer-1 aggregate + epilogue + 64x2 layer-2 GEMM (wave per dst)
    const int wv = t >> 6, j = t & 63;
    const float* __restrict__ hj = h1 + j;
    const float b1j = b1[j];
    const float w20 = W2[j * 2 + 0], w21 = W2[j * 2 + 1];
    const float s2a = a_s2[0], s2b = a_s2[1], d2a = a_d2[0], d2b = a_d2[1];

    for (int dl = wv; dl < nd; dl += 4) {
        const int n   = (b << 8) + dl;
        const int r0  = lstart[dl];
        const int deg = lstart[dl + 1] - r0;   // real in-edges; +1 implicit self
        const float ad = ad1[n];

        float acc = 0.f, den_l = 0.f;

        if (deg <= 63) {               // fast path: edges + self all in one wave chunk
            int   sj = n;              // lane deg holds the self edge
            float aj = (j == deg) ? as1[n] : -INFINITY;
            if (j < deg) { sj = lcsr[r0 + j]; aj = as1[sj]; }
            float rm = aj;
#pragma unroll
            for (int o = 32; o; o >>= 1) rm = fmaxf(rm, __shfl_xor(rm, o, 64));
            const float mv = lrelu(rm + ad);
            float pj = 0.f;
            if (j <= deg) pj = __expf(lrelu(aj + ad) - mv);
            den_l = pj;

            const int tot = deg + 1;
            int u = 0;
            for (; u + 4 <= tot; u += 4) {
                const int   s0 = __shfl(sj, u,     64), s1 = __shfl(sj, u + 1, 64),
                            s2 = __shfl(sj, u + 2, 64), s3 = __shfl(sj, u + 3, 64);
                const float p0 = __shfl(pj, u,     64), p1 = __shfl(pj, u + 1, 64),
                            p2 = __shfl(pj, u + 2, 64), p3 = __shfl(pj, u + 3, 64);
                const float v0 = hj[(size_t)s0 << 6], v1 = hj[(size_t)s1 << 6],
                            v2 = hj[(size_t)s2 << 6], v3 = hj[(size_t)s3 << 6];
                acc = fmaf(p0, v0, acc); acc = fmaf(p1, v1, acc);
                acc = fmaf(p2, v2, acc); acc = fmaf(p3, v3, acc);
            }
            for (; u < tot; ++u) {
                const int   s0 = __shfl(sj, u, 64);
                const float p0 = __shfl(pj, u, 64);
                acc = fmaf(p0, hj[(size_t)s0 << 6], acc);
            }
        } else {                       // generic chunked path + explicit self term
            float rml = (j == 0) ? as1[n] : -INFINITY;
            for (int idx = r0 + j; idx < r0 + deg; idx += 64) rml = fmaxf(rml, as1[lcsr[idx]]);
            float rm = rml;
#pragma unroll
            for (int o = 32; o; o >>= 1) rm = fmaxf(rm, __shfl_xor(rm, o, 64));
            const float mv = lrelu(rm + ad);

            // self edge
            {
                const float ps = __expf(lrelu(as1[n] + ad) - mv);
                if (j == 0) den_l += ps;
                acc = fmaf(ps, hj[(size_t)n << 6], acc);
            }
            for (int base = r0; base < r0 + deg; base += 64) {
                const int cnt = min(64, r0 + deg - base);
                int sj = 0; float pj = 0.f;
                if (j < cnt) { sj = lcsr[base + j]; pj = __expf(lrelu(as1[sj] + ad) - mv); }
                den_l += pj;
                int u = 0;
                for (; u + 4 <= cnt; u += 4) {
                    const int   s0 = __shfl(sj, u,     64), s1 = __shfl(sj, u + 1, 64),
                                s2 = __shfl(sj, u + 2, 64), s3 = __shfl(sj, u + 3, 64);
                    const float p0 = __shfl(pj, u,     64), p1 = __shfl(pj, u + 1, 64),
                                p2 = __shfl(pj, u + 2, 64), p3 = __shfl(pj, u + 3, 64);
                    const float v0 = hj[(size_t)s0 << 6], v1 = hj[(size_t)s1 << 6],
                                v2 = hj[(size_t)s2 << 6], v3 = hj[(size_t)s3 << 6];
                    acc = fmaf(p0, v0, acc); acc = fmaf(p1, v1, acc);
                    acc = fmaf(p2, v2, acc); acc = fmaf(p3, v3, acc);
                }
                for (; u < cnt; ++u) {
                    const int   s0 = __shfl(sj, u, 64);
                    const float p0 = __shfl(pj, u, 64);
                    acc = fmaf(p0, hj[(size_t)s0 << 6], acc);
                }
            }
        }

        float den = den_l;
#pragma unroll
        for (int o = 32; o; o >>= 1) den += __shfl_xor(den, o, 64);

        float v = acc / (den + 1e-16f) + b1j;
        v = v > 0.f ? v : 0.f;
        float c0 = v * w20, c1 = v * w21;
#pragma unroll
        for (int o = 32; o; o >>= 1) {
            c0 += __shfl_xor(c0, o, 64);
            c1 += __shfl_xor(c1, o, 64);
        }
        if (j == 0) {
            h2[n * 2 + 0] = c0;
            h2[n * 2 + 1] = c1;
            as2[n] = c0 * s2a + c1 * s2b;
            ad2[n] = c0 * d2a + c1 * d2b;
        }
    }
}

// ---------------- Layer-2 aggregate: thread per dst + implicit self edge ----------------
__global__ __launch_bounds__(256) void k_agg2_csr(
    const int* __restrict__ row_start, const int* __restrict__ csr,
    const float* __restrict__ as2, const float* __restrict__ ad2,
    const float* __restrict__ h2, const float* __restrict__ b2,
    float* __restrict__ out)
{
    const int n = blockIdx.x * 256 + threadIdx.x;
    if (n >= N_NODES) return;
    const int r0 = row_start[n], r1 = row_start[n + 1];
    const float ad = ad2[n];
    const float2* h22 = (const float2*)h2;

    float rm = as2[n];                         // self edge
    int idx = r0;
    for (; idx + 4 <= r1; idx += 4) {
        const int s0 = csr[idx], s1 = csr[idx + 1], s2 = csr[idx + 2], s3 = csr[idx + 3];
        const float a0 = as2[s0], a1 = as2[s1], a2 = as2[s2], a3 = as2[s3];
        rm = fmaxf(rm, fmaxf(fmaxf(a0, a1), fmaxf(a2, a3)));
    }
    for (; idx < r1; ++idx) rm = fmaxf(rm, as2[csr[idx]]);
    const float mv = lrelu(rm + ad);

    float den, x0, x1;
    {   // self edge
        const float p = __expf(lrelu(as2[n] + ad) - mv);
        const float2 g = h22[n];
        den = p; x0 = p * g.x; x1 = p * g.y;
    }
    idx = r0;
    for (; idx + 2 <= r1; idx += 2) {
        const int s0 = csr[idx], s1 = csr[idx + 1];
        const float  a0 = as2[s0], a1 = as2[s1];
        const float2 g0 = h22[s0], g1 = h22[s1];
        const float p0 = __expf(lrelu(a0 + ad) - mv);
        const float p1 = __expf(lrelu(a1 + ad) - mv);
        den += p0 + p1;
        x0 = fmaf(p0, g0.x, fmaf(p1, g1.x, x0));
        x1 = fmaf(p0, g0.y, fmaf(p1, g1.y, x1));
    }
    for (; idx < r1; ++idx) {
        const int s0 = csr[idx];
        const float p0 = __expf(lrelu(as2[s0] + ad) - mv);
        const float2 g0 = h22[s0];
        den += p0;
        x0 = fmaf(p0, g0.x, x0);
        x1 = fmaf(p0, g0.y, x1);
    }
    const float inv = 1.f / (den + 1e-16f);
    out[n * 2 + 0] = x0 * inv + b2[0];
    out[n * 2 + 1] = x1 * inv + b2[1];
}

extern "C" void kernel_launch(void* const* d_in, const int* in_sizes, int n_in,
                              void* d_out, int out_size, void* d_ws, size_t ws_size,
                              hipStream_t stream)
{
    const float* x    = (const float*)d_in[0];
    const int*   ei   = (const int*)d_in[1];
    const float* W1   = (const float*)d_in[2];
    const float* as1w = (const float*)d_in[3];
    const float* ad1w = (const float*)d_in[4];
    const float* b1   = (const float*)d_in[5];
    const float* W2   = (const float*)d_in[6];
    const float* as2w = (const float*)d_in[7];
    const float* ad2w = (const float*)d_in[8];
    const float* b2   = (const float*)d_in[9];
    float* out = (float*)d_out;

    float* ws = (float*)d_ws;
    size_t off = 0;
    float* h1  = ws + off; off += (size_t)N_NODES * F_H;
    float* as1 = ws + off; off += N_NODES;
    float* ad1 = ws + off; off += N_NODES;
    float* h2  = ws + off; off += (size_t)N_NODES * 2;
    float* as2 = ws + off; off += N_NODES;
    float* ad2 = ws + off; off += N_NODES;
    int* bcur      = (int*)(ws + off); off += NBUCK * SUB;
    int* boff      = (int*)(ws + off); off += NBUCK + 1;
    int* row_start = (int*)(ws + off); off += N_NODES + 1;
    int* csr       = (int*)(ws + off); off += N_EDGES;
    unsigned* buf  = (unsigned*)(ws + off); off += (size_t)NBUCK * SUB * SUBCAP;  // 12.8 MB

    hipMemsetAsync(bcur, 0, NBUCK * SUB * sizeof(int), stream);

    k_gemm1    <<<(N_NODES + 63) / 64, 64, 0, stream>>>(x, W1, as1w, ad1w, h1, as1, ad1);
    k_bucketize<<<(N_EDGES + 255) / 256, 256, 0, stream>>>(ei, bcur, buf);
    k_bscan    <<<1, 512, 0, stream>>>(bcur, boff);
    k_csr_agg1 <<<NBUCK, 256, 0, stream>>>(
        bcur, buf, boff, as1, ad1, h1, b1, W2, as2w, ad2w,
        row_start, csr, h2, as2, ad2);
    k_agg2_csr <<<NBUCK, 256, 0, stream>>>(row_start, csr, as2, ad2, h2, b2, out);
}

// Round 7
// 409.282 us; speedup vs baseline: 1.3606x; 1.3606x over previous
//
#include <hip/hip_runtime.h>
#include <math.h>

constexpr int N_NODES = 100000;
constexpr int N_EDGES = 1600000;
constexpr int F_IN    = 128;
constexpr int F_H     = 64;
constexpr float NEG_SLOPE = 0.2f;

constexpr int NBUCK  = (N_NODES + 255) / 256;  // 391 buckets of 256 dst nodes
constexpr int SUB    = 8;                      // sub-streams per bucket
constexpr int SUBCAP = 1024;                   // mean 512 real edges, +22 sigma
constexpr int LCAP   = 6144;                   // bucket mean 4096, +32 sigma

__device__ inline float lrelu(float v) { return v > 0.f ? v : NEG_SLOPE * v; }

// ---------------- GEMM: lane = row, W via wave-uniform scalar loads, no LDS ----------------
__global__ __launch_bounds__(64) void k_gemm1(
    const float* __restrict__ x, const float* __restrict__ W1,
    const float* __restrict__ a_s, const float* __restrict__ a_d,
    float* __restrict__ h1, float* __restrict__ as1, float* __restrict__ ad1)
{
    const int row = blockIdx.x * 64 + threadIdx.x;
    if (row >= N_NODES) return;

    float acc[F_H];
#pragma unroll
    for (int f = 0; f < F_H; ++f) acc[f] = 0.f;

    const float4* __restrict__ xr = (const float4*)(x + (size_t)row * F_IN);
    for (int k4 = 0; k4 < F_IN / 4; ++k4) {
        const float4 xv = xr[k4];
        const float* __restrict__ wk = W1 + (size_t)k4 * 4 * F_H;
#pragma unroll
        for (int kk = 0; kk < 4; ++kk) {
            const float xs = (kk == 0) ? xv.x : (kk == 1) ? xv.y : (kk == 2) ? xv.z : xv.w;
            const float* __restrict__ w = wk + kk * F_H;   // wave-uniform -> scalar loads
#pragma unroll
            for (int f = 0; f < F_H; ++f)
                acc[f] = fmaf(xs, w[f], acc[f]);
        }
    }

    float vs = 0.f, vd = 0.f;
#pragma unroll
    for (int f = 0; f < F_H; ++f) {
        vs = fmaf(acc[f], a_s[f], vs);
        vd = fmaf(acc[f], a_d[f], vd);
    }
    as1[row] = vs;
    ad1[row] = vd;

    float4* __restrict__ hr = (float4*)(h1 + (size_t)row * F_H);
#pragma unroll
    for (int q = 0; q < F_H / 4; ++q)
        hr[q] = make_float4(acc[4 * q], acc[4 * q + 1], acc[4 * q + 2], acc[4 * q + 3]);
}

// ---------------- Pass S1: bucketize REAL edges (self-loops implicit) ----------------
__global__ __launch_bounds__(256) void k_bucketize(
    const int* __restrict__ ei, int* __restrict__ bcur, unsigned* __restrict__ buf)
{
    const int i = blockIdx.x * 256 + threadIdx.x;
    if (i >= N_EDGES) return;
    const int s = ei[i], d = ei[N_EDGES + i];
    const int b = d >> 8;
    const int c = b * SUB + (blockIdx.x & (SUB - 1));
    const int pos = atomicAdd(&bcur[c], 1);
    if (pos < SUBCAP)
        buf[(size_t)c * SUBCAP + pos] = ((unsigned)s << 8) | (unsigned)(d & 255);
}

// ---------------- Bucket-total scan (391 values, one block) ----------------
__global__ __launch_bounds__(512) void k_bscan(const int* __restrict__ bcur, int* __restrict__ boff)
{
    __shared__ int sm[512];
    const int t = threadIdx.x;
    int m = 0;
    if (t < NBUCK) {
#pragma unroll
        for (int q = 0; q < SUB; ++q) m += min(bcur[t * SUB + q], SUBCAP);
    }
    sm[t] = m;
    __syncthreads();
    for (int o = 1; o < 512; o <<= 1) {
        int a = (t >= o) ? sm[t - o] : 0;
        __syncthreads();
        sm[t] += a;
        __syncthreads();
    }
    if (t < NBUCK) boff[t] = sm[t] - m;   // exclusive
}

// ---------------- Pass S2: per-bucket CSR build in LDS, dense global write ----------------
// 1024 threads: build is throughput work; strided over sub-streams.
__global__ __launch_bounds__(1024) void k_csr_build(
    const int* __restrict__ bcur, const unsigned* __restrict__ buf, const int* __restrict__ boff,
    int* __restrict__ row_start, int* __restrict__ csr)
{
    __shared__ int lcsr[LCAP];      // 24 KB
    __shared__ int hist[256];
    __shared__ int lstart[257];
    __shared__ int lcur[256];
    __shared__ int scnt[SUB];

    const int b  = blockIdx.x;
    const int t  = threadIdx.x;
    const int nd = min(256, N_NODES - (b << 8));

    if (t < 256) hist[t] = 0;
    if (t < SUB) scnt[t] = min(bcur[b * SUB + t], SUBCAP);
    __syncthreads();

    // 1. histogram of local dst
    for (int q = 0; q < SUB; ++q) {
        const unsigned* __restrict__ sb = buf + (size_t)(b * SUB + q) * SUBCAP;
        const int m = scnt[q];
        for (int i = t; i < m; i += 1024) atomicAdd(&hist[sb[i] & 255], 1);
    }
    __syncthreads();

    // 2. inclusive scan (first 256 threads)
    for (int o = 1; o < 256; o <<= 1) {
        int a = 0;
        if (t < 256 && t >= o) a = hist[t - o];
        __syncthreads();
        if (t < 256) hist[t] += a;
        __syncthreads();
    }
    if (t < 256) { lstart[t + 1] = hist[t]; lcur[t] = 0; }
    if (t == 0) lstart[0] = 0;
    __syncthreads();

    // 3. scatter src ids into LDS csr
    for (int q = 0; q < SUB; ++q) {
        const unsigned* __restrict__ sb = buf + (size_t)(b * SUB + q) * SUBCAP;
        const int m = scnt[q];
        for (int i = t; i < m; i += 1024) {
            const unsigned v = sb[i];
            const int dl = v & 255;
            const int p  = atomicAdd(&lcur[dl], 1);
            const int pp = lstart[dl] + p;
            if (pp < LCAP) lcsr[pp] = (int)(v >> 8);
        }
    }
    __syncthreads();

    // 4. dense global csr + row_start
    const int gb   = boff[b];
    const int mtot = lstart[256];
    for (int i = t; i < mtot; i += 1024) csr[gb + i] = lcsr[i];
    if (t < nd) row_start[(b << 8) + t + 1] = gb + lstart[t + 1];
    if (b == 0 && t == 0) row_start[0] = 0;
}

// ---------------- Layer-1 aggregate: wave per dst, implicit self, fused epilogue ----------------
__global__ __launch_bounds__(256) void k_agg1(
    const int* __restrict__ row_start, const int* __restrict__ csr,
    const float* __restrict__ as1, const float* __restrict__ ad1, const float* __restrict__ h1,
    const float* __restrict__ b1, const float* __restrict__ W2,
    const float* __restrict__ a_s2, const float* __restrict__ a_d2,
    float* __restrict__ h2, float* __restrict__ as2, float* __restrict__ ad2)
{
    const int n = blockIdx.x * 4 + (threadIdx.x >> 6);
    const int j = threadIdx.x & 63;
    if (n >= N_NODES) return;

    const int r0  = row_start[n];
    const int deg = row_start[n + 1] - r0;   // real in-edges; +1 implicit self
    const float ad = ad1[n];
    const float* __restrict__ hj = h1 + j;

    float acc = 0.f, den_l = 0.f;

    if (deg <= 63) {               // fast path: edges + self in one wave chunk
        int   sj = n;              // lane 'deg' holds the self edge
        float aj = (j == deg) ? as1[n] : -INFINITY;
        if (j < deg) { sj = csr[r0 + j]; aj = as1[sj]; }
        float rm = aj;
#pragma unroll
        for (int o = 32; o; o >>= 1) rm = fmaxf(rm, __shfl_xor(rm, o, 64));
        const float mv = lrelu(rm + ad);
        float pj = 0.f;
        if (j <= deg) pj = __expf(lrelu(aj + ad) - mv);
        den_l = pj;

        const int tot = deg + 1;
        int u = 0;
        for (; u + 4 <= tot; u += 4) {
            const int   s0 = __shfl(sj, u,     64), s1 = __shfl(sj, u + 1, 64),
                        s2 = __shfl(sj, u + 2, 64), s3 = __shfl(sj, u + 3, 64);
            const float p0 = __shfl(pj, u,     64), p1 = __shfl(pj, u + 1, 64),
                        p2 = __shfl(pj, u + 2, 64), p3 = __shfl(pj, u + 3, 64);
            const float v0 = hj[(size_t)s0 << 6], v1 = hj[(size_t)s1 << 6],
                        v2 = hj[(size_t)s2 << 6], v3 = hj[(size_t)s3 << 6];
            acc = fmaf(p0, v0, acc); acc = fmaf(p1, v1, acc);
            acc = fmaf(p2, v2, acc); acc = fmaf(p3, v3, acc);
        }
        for (; u < tot; ++u) {
            const int   s0 = __shfl(sj, u, 64);
            const float p0 = __shfl(pj, u, 64);
            acc = fmaf(p0, hj[(size_t)s0 << 6], acc);
        }
    } else {                       // generic chunked path + explicit self term
        float rml = (j == 0) ? as1[n] : -INFINITY;
        for (int idx = r0 + j; idx < r0 + deg; idx += 64) rml = fmaxf(rml, as1[csr[idx]]);
        float rm = rml;
#pragma unroll
        for (int o = 32; o; o >>= 1) rm = fmaxf(rm, __shfl_xor(rm, o, 64));
        const float mv = lrelu(rm + ad);

        {   // self edge
            const float ps = __expf(lrelu(as1[n] + ad) - mv);
            if (j == 0) den_l += ps;
            acc = fmaf(ps, hj[(size_t)n << 6], acc);
        }
        for (int base = r0; base < r0 + deg; base += 64) {
            const int cnt = min(64, r0 + deg - base);
            int sj = 0; float pj = 0.f;
            if (j < cnt) { sj = csr[base + j]; pj = __expf(lrelu(as1[sj] + ad) - mv); }
            den_l += pj;
            int u = 0;
            for (; u + 4 <= cnt; u += 4) {
                const int   s0 = __shfl(sj, u,     64), s1 = __shfl(sj, u + 1, 64),
                            s2 = __shfl(sj, u + 2, 64), s3 = __shfl(sj, u + 3, 64);
                const float p0 = __shfl(pj, u,     64), p1 = __shfl(pj, u + 1, 64),
                            p2 = __shfl(pj, u + 2, 64), p3 = __shfl(pj, u + 3, 64);
                const float v0 = hj[(size_t)s0 << 6], v1 = hj[(size_t)s1 << 6],
                            v2 = hj[(size_t)s2 << 6], v3 = hj[(size_t)s3 << 6];
                acc = fmaf(p0, v0, acc); acc = fmaf(p1, v1, acc);
                acc = fmaf(p2, v2, acc); acc = fmaf(p3, v3, acc);
            }
            for (; u < cnt; ++u) {
                const int   s0 = __shfl(sj, u, 64);
                const float p0 = __shfl(pj, u, 64);
                acc = fmaf(p0, hj[(size_t)s0 << 6], acc);
            }
        }
    }

    float den = den_l;
#pragma unroll
    for (int o = 32; o; o >>= 1) den += __shfl_xor(den, o, 64);

    // layer-1 epilogue + 64x2 layer-2 GEMM + alpha2
    float v = acc / (den + 1e-16f) + b1[j];
    v = v > 0.f ? v : 0.f;
    float c0 = v * W2[j * 2 + 0];
    float c1 = v * W2[j * 2 + 1];
#pragma unroll
    for (int o = 32; o; o >>= 1) {
        c0 += __shfl_xor(c0, o, 64);
        c1 += __shfl_xor(c1, o, 64);
    }
    if (j == 0) {
        h2[n * 2 + 0] = c0;
        h2[n * 2 + 1] = c1;
        as2[n] = c0 * a_s2[0] + c1 * a_s2[1];
        ad2[n] = c0 * a_d2[0] + c1 * a_d2[1];
    }
}

// ---------------- Layer-2 aggregate: thread per dst + implicit self edge ----------------
__global__ __launch_bounds__(256) void k_agg2_csr(
    const int* __restrict__ row_start, const int* __restrict__ csr,
    const float* __restrict__ as2, const float* __restrict__ ad2,
    const float* __restrict__ h2, const float* __restrict__ b2,
    float* __restrict__ out)
{
    const int n = blockIdx.x * 256 + threadIdx.x;
    if (n >= N_NODES) return;
    const int r0 = row_start[n], r1 = row_start[n + 1];
    const float ad = ad2[n];
    const float2* h22 = (const float2*)h2;

    float rm = as2[n];                         // self edge
    int idx = r0;
    for (; idx + 4 <= r1; idx += 4) {
        const int s0 = csr[idx], s1 = csr[idx + 1], s2 = csr[idx + 2], s3 = csr[idx + 3];
        const float a0 = as2[s0], a1 = as2[s1], a2 = as2[s2], a3 = as2[s3];
        rm = fmaxf(rm, fmaxf(fmaxf(a0, a1), fmaxf(a2, a3)));
    }
    for (; idx < r1; ++idx) rm = fmaxf(rm, as2[csr[idx]]);
    const float mv = lrelu(rm + ad);

    float den, x0, x1;
    {   // self edge
        const float p = __expf(lrelu(as2[n] + ad) - mv);
        const float2 g = h22[n];
        den = p; x0 = p * g.x; x1 = p * g.y;
    }
    idx = r0;
    for (; idx + 2 <= r1; idx += 2) {
        const int s0 = csr[idx], s1 = csr[idx + 1];
        const float  a0 = as2[s0], a1 = as2[s1];
        const float2 g0 = h22[s0], g1 = h22[s1];
        const float p0 = __expf(lrelu(a0 + ad) - mv);
        const float p1 = __expf(lrelu(a1 + ad) - mv);
        den += p0 + p1;
        x0 = fmaf(p0, g0.x, fmaf(p1, g1.x, x0));
        x1 = fmaf(p0, g0.y, fmaf(p1, g1.y, x1));
    }
    for (; idx < r1; ++idx) {
        const int s0 = csr[idx];
        const float p0 = __expf(lrelu(as2[s0] + ad) - mv);
        const float2 g0 = h22[s0];
        den += p0;
        x0 = fmaf(p0, g0.x, x0);
        x1 = fmaf(p0, g0.y, x1);
    }
    const float inv = 1.f / (den + 1e-16f);
    out[n * 2 + 0] = x0 * inv + b2[0];
    out[n * 2 + 1] = x1 * inv + b2[1];
}

extern "C" void kernel_launch(void* const* d_in, const int* in_sizes, int n_in,
                              void* d_out, int out_size, void* d_ws, size_t ws_size,
                              hipStream_t stream)
{
    const float* x    = (const float*)d_in[0];
    const int*   ei   = (const int*)d_in[1];
    const float* W1   = (const float*)d_in[2];
    const float* as1w = (const float*)d_in[3];
    const float* ad1w = (const float*)d_in[4];
    const float* b1   = (const float*)d_in[5];
    const float* W2   = (const float*)d_in[6];
    const float* as2w = (const float*)d_in[7];
    const float* ad2w = (const float*)d_in[8];
    const float* b2   = (const float*)d_in[9];
    float* out = (float*)d_out;

    float* ws = (float*)d_ws;
    size_t off = 0;
    float* h1  = ws + off; off += (size_t)N_NODES * F_H;
    float* as1 = ws + off; off += N_NODES;
    float* ad1 = ws + off; off += N_NODES;
    float* h2  = ws + off; off += (size_t)N_NODES * 2;
    float* as2 = ws + off; off += N_NODES;
    float* ad2 = ws + off; off += N_NODES;
    int* bcur      = (int*)(ws + off); off += NBUCK * SUB;
    int* boff      = (int*)(ws + off); off += NBUCK + 1;
    int* row_start = (int*)(ws + off); off += N_NODES + 1;
    int* csr       = (int*)(ws + off); off += N_EDGES;
    unsigned* buf  = (unsigned*)(ws + off); off += (size_t)NBUCK * SUB * SUBCAP;  // 12.8 MB

    hipMemsetAsync(bcur, 0, NBUCK * SUB * sizeof(int), stream);

    k_gemm1    <<<(N_NODES + 63) / 64, 64, 0, stream>>>(x, W1, as1w, ad1w, h1, as1, ad1);
    k_bucketize<<<(N_EDGES + 255) / 256, 256, 0, stream>>>(ei, bcur, buf);
    k_bscan    <<<1, 512, 0, stream>>>(bcur, boff);
    k_csr_build<<<NBUCK, 1024, 0, stream>>>(bcur, buf, boff, row_start, csr);
    k_agg1     <<<(N_NODES + 3) / 4, 256, 0, stream>>>(
        row_start, csr, as1, ad1, h1, b1, W2, as2w, ad2w, h2, as2, ad2);
    k_agg2_csr <<<NBUCK, 256, 0, stream>>>(row_start, csr, as2, ad2, h2, b2, out);
}

// Round 8
// 313.062 us; speedup vs baseline: 1.7788x; 1.3074x over previous
//
#include <hip/hip_runtime.h>
#include <math.h>

constexpr int N_NODES = 100000;
constexpr int N_EDGES = 1600000;
constexpr int F_IN    = 128;
constexpr int F_H     = 64;
constexpr float NEG_SLOPE = 0.2f;

constexpr int NBUCK  = (N_NODES + 255) / 256;  // 391 buckets of 256 dst nodes
constexpr int BUFCAP = 6144;                   // per-bucket stream cap (mean 4092, +32 sigma)
constexpr int LCAP   = 6144;
constexpr int CPAD   = 16;                     // gcur stride in ints: one 64B line per counter

// staged multisplit params
constexpr int SB   = 64;                       // persistent staging blocks
constexpr int EPT  = 4;                        // edges per thread per round
constexpr int EPR  = 256 * EPT;                // 1024 edges per round
constexpr int G    = 16;                       // flush granularity = one 64B line
constexpr int BCAP = 48;                       // LDS bin capacity (15 carry + Poisson(2.62) tail)

__device__ inline float lrelu(float v) { return v > 0.f ? v : NEG_SLOPE * v; }

// ---------------- GEMM: lane = row, W via wave-uniform scalar loads, no LDS ----------------
__global__ __launch_bounds__(64) void k_gemm1(
    const float* __restrict__ x, const float* __restrict__ W1,
    const float* __restrict__ a_s, const float* __restrict__ a_d,
    float* __restrict__ h1, float* __restrict__ as1, float* __restrict__ ad1)
{
    const int row = blockIdx.x * 64 + threadIdx.x;
    if (row >= N_NODES) return;

    float acc[F_H];
#pragma unroll
    for (int f = 0; f < F_H; ++f) acc[f] = 0.f;

    const float4* __restrict__ xr = (const float4*)(x + (size_t)row * F_IN);
    for (int k4 = 0; k4 < F_IN / 4; ++k4) {
        const float4 xv = xr[k4];
        const float* __restrict__ wk = W1 + (size_t)k4 * 4 * F_H;
#pragma unroll
        for (int kk = 0; kk < 4; ++kk) {
            const float xs = (kk == 0) ? xv.x : (kk == 1) ? xv.y : (kk == 2) ? xv.z : xv.w;
            const float* __restrict__ w = wk + kk * F_H;   // wave-uniform -> scalar loads
#pragma unroll
            for (int f = 0; f < F_H; ++f)
                acc[f] = fmaf(xs, w[f], acc[f]);
        }
    }

    float vs = 0.f, vd = 0.f;
#pragma unroll
    for (int f = 0; f < F_H; ++f) {
        vs = fmaf(acc[f], a_s[f], vs);
        vd = fmaf(acc[f], a_d[f], vd);
    }
    as1[row] = vs;
    ad1[row] = vd;

    float4* __restrict__ hr = (float4*)(h1 + (size_t)row * F_H);
#pragma unroll
    for (int q = 0; q < F_H / 4; ++q)
        hr[q] = make_float4(acc[4 * q], acc[4 * q + 1], acc[4 * q + 2], acc[4 * q + 3]);
}

// ---------------- Staged multisplit bucketize: LDS bins, aligned 16-dword flushes ----------------
__global__ __launch_bounds__(256) void k_bucketize_staged(
    const int* __restrict__ ei, int* __restrict__ gcur, unsigned* __restrict__ buf)
{
    __shared__ unsigned bin_buf[NBUCK][BCAP];   // ~75 KB
    __shared__ int bin_cnt[NBUCK];

    const int t = threadIdx.x;
    for (int i = t; i < NBUCK; i += 256) bin_cnt[i] = 0;
    __syncthreads();

    const int per = N_EDGES / SB;               // 25000 exactly
    const int e0 = blockIdx.x * per;
    const int e1 = (blockIdx.x == SB - 1) ? N_EDGES : (e0 + per);

    int cs[EPT], cd[EPT];
#pragma unroll
    for (int q = 0; q < EPT; ++q) {
        const int i = e0 + q * 256 + t;
        cs[q] = (i < e1) ? ei[i] : -1;
        cd[q] = (i < e1) ? ei[N_EDGES + i] : 0;
    }

    for (int base = e0; base < e1; base += EPR) {
        int ls[EPT], ld[EPT];
#pragma unroll
        for (int q = 0; q < EPT; ++q) { ls[q] = cs[q]; ld[q] = cd[q]; }
        const int nbase = base + EPR;
        if (nbase < e1) {
#pragma unroll
            for (int q = 0; q < EPT; ++q) {
                const int i = nbase + q * 256 + t;
                cs[q] = (i < e1) ? ei[i] : -1;
                cd[q] = (i < e1) ? ei[N_EDGES + i] : 0;
            }
        }
        // insert into LDS bins
#pragma unroll
        for (int q = 0; q < EPT; ++q) {
            if (ls[q] >= 0) {
                const int b = ld[q] >> 8;
                const int pos = atomicAdd(&bin_cnt[b], 1);
                if (pos < BCAP)
                    bin_buf[b][pos] = ((unsigned)ls[q] << 8) | (unsigned)(ld[q] & 255);
            }
        }
        __syncthreads();
        // flush full 16-groups (aligned claims -> full-line writes)
        for (int bb = t; bb < NBUCK; bb += 256) {
            const int cnt = bin_cnt[bb];
            if (cnt >= G) {
                const int take = cnt & ~(G - 1);
                const int gbase = atomicAdd(&gcur[bb * CPAD], take);
                if (gbase + take <= BUFCAP) {
                    unsigned* __restrict__ dst = buf + (size_t)bb * BUFCAP + gbase;
                    const int src0 = cnt - take;
                    for (int u = 0; u < take; u += 4) {
                        uint4 v;
                        v.x = bin_buf[bb][src0 + u];
                        v.y = bin_buf[bb][src0 + u + 1];
                        v.z = bin_buf[bb][src0 + u + 2];
                        v.w = bin_buf[bb][src0 + u + 3];
                        *(uint4*)(dst + u) = v;
                    }
                }
                bin_cnt[bb] = cnt - take;
            }
        }
        __syncthreads();
    }
    // drain partial bins
    for (int bb = t; bb < NBUCK; bb += 256) {
        const int cnt = bin_cnt[bb];
        if (cnt > 0) {
            const int gbase = atomicAdd(&gcur[bb * CPAD], cnt);
            if (gbase + cnt <= BUFCAP) {
                unsigned* __restrict__ dst = buf + (size_t)bb * BUFCAP + gbase;
                for (int u = 0; u < cnt; ++u) dst[u] = bin_buf[bb][u];
            }
        }
    }
}

// ---------------- Bucket-total scan (391 values, one block) ----------------
__global__ __launch_bounds__(512) void k_bscan(const int* __restrict__ gcur, int* __restrict__ boff)
{
    __shared__ int sm[512];
    const int t = threadIdx.x;
    const int m = (t < NBUCK) ? min(gcur[t * CPAD], BUFCAP) : 0;
    sm[t] = m;
    __syncthreads();
    for (int o = 1; o < 512; o <<= 1) {
        int a = (t >= o) ? sm[t - o] : 0;
        __syncthreads();
        sm[t] += a;
        __syncthreads();
    }
    if (t < NBUCK) boff[t] = sm[t] - m;   // exclusive
}

// ---------------- Per-bucket CSR build in LDS, dense global write ----------------
__global__ __launch_bounds__(1024) void k_csr_build(
    const int* __restrict__ gcur, const unsigned* __restrict__ buf, const int* __restrict__ boff,
    int* __restrict__ row_start, int* __restrict__ csr)
{
    __shared__ int lcsr[LCAP];      // 24 KB
    __shared__ int hist[256];
    __shared__ int lstart[257];
    __shared__ int lcur[256];

    const int b  = blockIdx.x;
    const int t  = threadIdx.x;
    const int nd = min(256, N_NODES - (b << 8));
    const int m  = min(gcur[b * CPAD], BUFCAP);
    const unsigned* __restrict__ sb = buf + (size_t)b * BUFCAP;

    if (t < 256) hist[t] = 0;
    __syncthreads();

    for (int i = t; i < m; i += 1024) atomicAdd(&hist[sb[i] & 255], 1);
    __syncthreads();

    for (int o = 1; o < 256; o <<= 1) {
        int a = 0;
        if (t < 256 && t >= o) a = hist[t - o];
        __syncthreads();
        if (t < 256) hist[t] += a;
        __syncthreads();
    }
    if (t < 256) { lstart[t + 1] = hist[t]; lcur[t] = 0; }
    if (t == 0) lstart[0] = 0;
    __syncthreads();

    for (int i = t; i < m; i += 1024) {
        const unsigned v = sb[i];
        const int dl = v & 255;
        const int p  = atomicAdd(&lcur[dl], 1);
        const int pp = lstart[dl] + p;
        if (pp < LCAP) lcsr[pp] = (int)(v >> 8);
    }
    __syncthreads();

    const int gb   = boff[b];
    const int mtot = lstart[256];
    for (int i = t; i < mtot; i += 1024) csr[gb + i] = lcsr[i];
    if (t < nd) row_start[(b << 8) + t + 1] = gb + lstart[t + 1];
    if (b == 0 && t == 0) row_start[0] = 0;
}

// ---------------- Layer-1 aggregate: wave per dst, implicit self, fused epilogue ----------------
__global__ __launch_bounds__(256) void k_agg1(
    const int* __restrict__ row_start, const int* __restrict__ csr,
    const float* __restrict__ as1, const float* __restrict__ ad1, const float* __restrict__ h1,
    const float* __restrict__ b1, const float* __restrict__ W2,
    const float* __restrict__ a_s2, const float* __restrict__ a_d2,
    float* __restrict__ h2, float* __restrict__ as2, float* __restrict__ ad2)
{
    const int n = blockIdx.x * 4 + (threadIdx.x >> 6);
    const int j = threadIdx.x & 63;
    if (n >= N_NODES) return;

    const int r0  = row_start[n];
    const int deg = row_start[n + 1] - r0;   // real in-edges; +1 implicit self
    const float ad = ad1[n];
    const float* __restrict__ hj = h1 + j;

    float acc = 0.f, den_l = 0.f;

    if (deg <= 63) {               // fast path: edges + self in one wave chunk
        int   sj = n;              // lane 'deg' holds the self edge
        float aj = (j == deg) ? as1[n] : -INFINITY;
        if (j < deg) { sj = csr[r0 + j]; aj = as1[sj]; }
        float rm = aj;
#pragma unroll
        for (int o = 32; o; o >>= 1) rm = fmaxf(rm, __shfl_xor(rm, o, 64));
        const float mv = lrelu(rm + ad);
        float pj = 0.f;
        if (j <= deg) pj = __expf(lrelu(aj + ad) - mv);
        den_l = pj;

        const int tot = deg + 1;
        int u = 0;
        for (; u + 4 <= tot; u += 4) {
            const int   s0 = __shfl(sj, u,     64), s1 = __shfl(sj, u + 1, 64),
                        s2 = __shfl(sj, u + 2, 64), s3 = __shfl(sj, u + 3, 64);
            const float p0 = __shfl(pj, u,     64), p1 = __shfl(pj, u + 1, 64),
                        p2 = __shfl(pj, u + 2, 64), p3 = __shfl(pj, u + 3, 64);
            const float v0 = hj[(size_t)s0 << 6], v1 = hj[(size_t)s1 << 6],
                        v2 = hj[(size_t)s2 << 6], v3 = hj[(size_t)s3 << 6];
            acc = fmaf(p0, v0, acc); acc = fmaf(p1, v1, acc);
            acc = fmaf(p2, v2, acc); acc = fmaf(p3, v3, acc);
        }
        for (; u < tot; ++u) {
            const int   s0 = __shfl(sj, u, 64);
            const float p0 = __shfl(pj, u, 64);
            acc = fmaf(p0, hj[(size_t)s0 << 6], acc);
        }
    } else {                       // generic chunked path + explicit self term
        float rml = (j == 0) ? as1[n] : -INFINITY;
        for (int idx = r0 + j; idx < r0 + deg; idx += 64) rml = fmaxf(rml, as1[csr[idx]]);
        float rm = rml;
#pragma unroll
        for (int o = 32; o; o >>= 1) rm = fmaxf(rm, __shfl_xor(rm, o, 64));
        const float mv = lrelu(rm + ad);

        {   // self edge
            const float ps = __expf(lrelu(as1[n] + ad) - mv);
            if (j == 0) den_l += ps;
            acc = fmaf(ps, hj[(size_t)n << 6], acc);
        }
        for (int base = r0; base < r0 + deg; base += 64) {
            const int cnt = min(64, r0 + deg - base);
            int sj = 0; float pj = 0.f;
            if (j < cnt) { sj = csr[base + j]; pj = __expf(lrelu(as1[sj] + ad) - mv); }
            den_l += pj;
            int u = 0;
            for (; u + 4 <= cnt; u += 4) {
                const int   s0 = __shfl(sj, u,     64), s1 = __shfl(sj, u + 1, 64),
                            s2 = __shfl(sj, u + 2, 64), s3 = __shfl(sj, u + 3, 64);
                const float p0 = __shfl(pj, u,     64), p1 = __shfl(pj, u + 1, 64),
                            p2 = __shfl(pj, u + 2, 64), p3 = __shfl(pj, u + 3, 64);
                const float v0 = hj[(size_t)s0 << 6], v1 = hj[(size_t)s1 << 6],
                            v2 = hj[(size_t)s2 << 6], v3 = hj[(size_t)s3 << 6];
                acc = fmaf(p0, v0, acc); acc = fmaf(p1, v1, acc);
                acc = fmaf(p2, v2, acc); acc = fmaf(p3, v3, acc);
            }
            for (; u < cnt; ++u) {
                const int   s0 = __shfl(sj, u, 64);
                const float p0 = __shfl(pj, u, 64);
                acc = fmaf(p0, hj[(size_t)s0 << 6], acc);
            }
        }
    }

    float den = den_l;
#pragma unroll
    for (int o = 32; o; o >>= 1) den += __shfl_xor(den, o, 64);

    // layer-1 epilogue + 64x2 layer-2 GEMM + alpha2
    float v = acc / (den + 1e-16f) + b1[j];
    v = v > 0.f ? v : 0.f;
    float c0 = v * W2[j * 2 + 0];
    float c1 = v * W2[j * 2 + 1];
#pragma unroll
    for (int o = 32; o; o >>= 1) {
        c0 += __shfl_xor(c0, o, 64);
        c1 += __shfl_xor(c1, o, 64);
    }
    if (j == 0) {
        h2[n * 2 + 0] = c0;
        h2[n * 2 + 1] = c1;
        as2[n] = c0 * a_s2[0] + c1 * a_s2[1];
        ad2[n] = c0 * a_d2[0] + c1 * a_d2[1];
    }
}

// ---------------- Layer-2 aggregate: thread per dst + implicit self edge ----------------
__global__ __launch_bounds__(256) void k_agg2_csr(
    const int* __restrict__ row_start, const int* __restrict__ csr,
    const float* __restrict__ as2, const float* __restrict__ ad2,
    const float* __restrict__ h2, const float* __restrict__ b2,
    float* __restrict__ out)
{
    const int n = blockIdx.x * 256 + threadIdx.x;
    if (n >= N_NODES) return;
    const int r0 = row_start[n], r1 = row_start[n + 1];
    const float ad = ad2[n];
    const float2* h22 = (const float2*)h2;

    float rm = as2[n];                         // self edge
    int idx = r0;
    for (; idx + 4 <= r1; idx += 4) {
        const int s0 = csr[idx], s1 = csr[idx + 1], s2 = csr[idx + 2], s3 = csr[idx + 3];
        const float a0 = as2[s0], a1 = as2[s1], a2 = as2[s2], a3 = as2[s3];
        rm = fmaxf(rm, fmaxf(fmaxf(a0, a1), fmaxf(a2, a3)));
    }
    for (; idx < r1; ++idx) rm = fmaxf(rm, as2[csr[idx]]);
    const float mv = lrelu(rm + ad);

    float den, x0, x1;
    {   // self edge
        const float p = __expf(lrelu(as2[n] + ad) - mv);
        const float2 g = h22[n];
        den = p; x0 = p * g.x; x1 = p * g.y;
    }
    idx = r0;
    for (; idx + 2 <= r1; idx += 2) {
        const int s0 = csr[idx], s1 = csr[idx + 1];
        const float  a0 = as2[s0], a1 = as2[s1];
        const float2 g0 = h22[s0], g1 = h22[s1];
        const float p0 = __expf(lrelu(a0 + ad) - mv);
        const float p1 = __expf(lrelu(a1 + ad) - mv);
        den += p0 + p1;
        x0 = fmaf(p0, g0.x, fmaf(p1, g1.x, x0));
        x1 = fmaf(p0, g0.y, fmaf(p1, g1.y, x1));
    }
    for (; idx < r1; ++idx) {
        const int s0 = csr[idx];
        const float p0 = __expf(lrelu(as2[s0] + ad) - mv);
        const float2 g0 = h22[s0];
        den += p0;
        x0 = fmaf(p0, g0.x, x0);
        x1 = fmaf(p0, g0.y, x1);
    }
    const float inv = 1.f / (den + 1e-16f);
    out[n * 2 + 0] = x0 * inv + b2[0];
    out[n * 2 + 1] = x1 * inv + b2[1];
}

extern "C" void kernel_launch(void* const* d_in, const int* in_sizes, int n_in,
                              void* d_out, int out_size, void* d_ws, size_t ws_size,
                              hipStream_t stream)
{
    const float* x    = (const float*)d_in[0];
    const int*   ei   = (const int*)d_in[1];
    const float* W1   = (const float*)d_in[2];
    const float* as1w = (const float*)d_in[3];
    const float* ad1w = (const float*)d_in[4];
    const float* b1   = (const float*)d_in[5];
    const float* W2   = (const float*)d_in[6];
    const float* as2w = (const float*)d_in[7];
    const float* ad2w = (const float*)d_in[8];
    const float* b2   = (const float*)d_in[9];
    float* out = (float*)d_out;

    float* ws = (float*)d_ws;
    size_t off = 0;
    float* h1  = ws + off; off += (size_t)N_NODES * F_H;   // 25.6 MB
    float* as1 = ws + off; off += N_NODES;
    float* ad1 = ws + off; off += N_NODES;
    float* h2  = ws + off; off += (size_t)N_NODES * 2;
    float* as2 = ws + off; off += N_NODES;
    float* ad2 = ws + off; off += N_NODES;
    // off = 7,000,000 floats -> 16B aligned
    int* gcur      = (int*)(ws + off); off += NBUCK * CPAD;              // 25 KB, zeroed
    unsigned* buf  = (unsigned*)(ws + off); off += (size_t)NBUCK * BUFCAP;  // 9.6 MB (16B-aligned)
    int* boff      = (int*)(ws + off); off += NBUCK + 1;
    int* row_start = (int*)(ws + off); off += N_NODES + 1;
    int* csr       = (int*)(ws + off); off += N_EDGES;

    hipMemsetAsync(gcur, 0, NBUCK * CPAD * sizeof(int), stream);

    k_gemm1           <<<(N_NODES + 63) / 64, 64, 0, stream>>>(x, W1, as1w, ad1w, h1, as1, ad1);
    k_bucketize_staged<<<SB, 256, 0, stream>>>(ei, gcur, buf);
    k_bscan           <<<1, 512, 0, stream>>>(gcur, boff);
    k_csr_build       <<<NBUCK, 1024, 0, stream>>>(gcur, buf, boff, row_start, csr);
    k_agg1            <<<(N_NODES + 3) / 4, 256, 0, stream>>>(
        row_start, csr, as1, ad1, h1, b1, W2, as2w, ad2w, h2, as2, ad2);
    k_agg2_csr        <<<NBUCK, 256, 0, stream>>>(row_start, csr, as2, ad2, h2, b2, out);
}